// Round 9
// baseline (255.129 us; speedup 1.0000x reference)
//
#include <hip/hip_runtime.h>

#define N_NODES 100000
#define N_EDGES 1000000
#define DEG_CAP 64
#define OVF_CAP 4096
#define SPILL_CAP 4096

// binning geometry
#define BKT_SH 8
#define BKT_NODES 256            // nodes per bucket
#define NBKT 392                 // 392*256 = 100352 >= N_NODES
#define BKT_CAP 4096             // record capacity per bucket (mean ~2551)
#define BIN_CHUNK 4096           // edges per bin block
#define FIFO_CAP 32              // LDS fifo depth per bucket (mean ~10.4)

typedef __attribute__((ext_vector_type(8))) short bf16x8;
typedef __attribute__((ext_vector_type(4))) float f32x4;

__device__ __forceinline__ unsigned short f2bf(float f) {
    unsigned u = __float_as_uint(f);
    return (unsigned short)((u + 0x7FFF + ((u >> 16) & 1)) >> 16);
}
__device__ __forceinline__ float bf2f(unsigned short b) {
    return __uint_as_float(((unsigned)b) << 16);
}
__device__ __forceinline__ float bflo(unsigned u) {   // low bf16 of a dword
    return __uint_as_float(u << 16);
}
__device__ __forceinline__ float bfhi(unsigned u) {   // high bf16 of a dword
    return __uint_as_float(u & 0xffff0000u);
}
// rounded hi + rounded residual lo: hi is BIT-IDENTICAL to f2bf(f) (the
// gather source), and hi+lo reconstructs f to ~2^-17 relative.
__device__ __forceinline__ void split_rbf(float f, unsigned short& ho,
                                          unsigned short& lo) {
    unsigned short hb = f2bf(f);
    ho = hb;
    lo = f2bf(f - bf2f(hb));
}

// ws layout (4B units) — AUDITED (u16 plane = N*64 u16 = 3,200,000 dwords):
//   counts : [0, 100352)
//   ovfc 100352 ; spillc 100353
//   gcur   : [100416, 100928)
//   ovf    : [100928, 109120)
//   spill  : [109120, 117312)
//   Bf1    : s16 [117312, 133696)
//   Bf2    : s16 [133696, 150080)
//   slots  : [150080, 6572608)        100352*64 dwords
//   rec    : u32 [6572608, 8178240)   392*4096
//   xh     : u16 [8178240,  11378240) 3.2M dwords = 6.4M u16
//   xl     : u16 [11378240, 14578240)
//   mh     : u16 [14578240, 17778240)
//   ml     : u16 [17778240, 20978240)
//   p_bf   : u16 [20978240, 24178240)
//   q      : f32 [24178240, 30578240)
// total 30,578,240 dwords = 122.3 MB

// Merged init + weight-split + x -> rounded-hi/residual-lo planes.
__global__ __launch_bounds__(256) void prep_kernel(
        const float4* __restrict__ x4,
        ushort4* __restrict__ xh4, ushort4* __restrict__ xl4,
        const float* __restrict__ W1l, const float* __restrict__ W1r,
        const float* __restrict__ W2l, const float* __restrict__ W2r,
        short* __restrict__ Bf1, short* __restrict__ Bf2,
        int4* __restrict__ gcur4, int* __restrict__ ovfc,
        int* __restrict__ spillc) {
    int i = blockIdx.x * blockDim.x + threadIdx.x;
    if (i < 128) gcur4[i] = make_int4(0, 0, 0, 0);
    if (i == 0) { *ovfc = 0; *spillc = 0; }
    if (i < 32768) {
        int g = i >> 14;
        int e = i & 16383;
        int k = e >> 7;
        int n = e & 127;
        float v;
        if (g == 0) v = (k < 64) ? W1l[k * 128 + n] : W1r[(k - 64) * 128 + n];
        else        v = (n < 64) ? W2l[k * 64 + n]  : W2r[k * 64 + (n - 64)];
        unsigned short hb, lb;
        split_rbf(v, hb, lb);
        int c = n >> 4, kc = k >> 5;
        int lane = (((k >> 3) & 3) << 4) | (n & 15);
        int j = k & 7;
        short* base = g ? Bf2 : Bf1;
        base[((c * 4 + kc) * 2 + 0) * 512 + lane * 8 + j] = (short)hb;
        base[((c * 4 + kc) * 2 + 1) * 512 + lane * 8 + j] = (short)lb;
    }
    if (i < N_NODES * 16) {
        float4 v = x4[i];
        ushort4 oh, ol;
        split_rbf(v.x, oh.x, ol.x);
        split_rbf(v.y, oh.y, ol.y);
        split_rbf(v.z, oh.z, ol.z);
        split_rbf(v.w, oh.w, ol.w);
        xh4[i] = oh;
        xl4[i] = ol;
    }
}

// Pass A: bin edges into 392 dst-range buckets via LDS FIFOs.
__global__ __launch_bounds__(256) void bin_kernel(
        const int* __restrict__ ei, unsigned* __restrict__ rec,
        int* __restrict__ gcur, int* __restrict__ spillc,
        int2* __restrict__ spill) {
    __shared__ int lcnt[NBKT];
    __shared__ unsigned fifo[NBKT * FIFO_CAP];   // 50KB
    for (int i = threadIdx.x; i < NBKT; i += 256) lcnt[i] = 0;
    __syncthreads();
    int base = blockIdx.x * BIN_CHUNK;
    int end = base + BIN_CHUNK;
    if (end > N_EDGES) end = N_EDGES;
    for (int e = base + threadIdx.x; e < end; e += 256) {
        int s = ei[e];
        int d = ei[N_EDGES + e];
        int b = d >> BKT_SH;
        unsigned r = ((unsigned)s << BKT_SH) | (unsigned)(d & (BKT_NODES - 1));
        int pos = atomicAdd(&lcnt[b], 1);
        if (pos < FIFO_CAP) {
            fifo[b * FIFO_CAP + pos] = r;
        } else {
            int o = atomicAdd(spillc, 1);
            if (o < SPILL_CAP) spill[o] = make_int2(s, d);
        }
    }
    __syncthreads();
    for (int b = threadIdx.x; b < NBKT; b += 256) {
        int cnt = lcnt[b];
        if (cnt > FIFO_CAP) cnt = FIFO_CAP;
        if (cnt == 0) continue;
        int gb = atomicAdd(&gcur[b], cnt);
        for (int k = 0; k < cnt; ++k) {
            int g = gb + k;
            unsigned r = fifo[b * FIFO_CAP + k];
            if (g < BKT_CAP) {
                rec[b * BKT_CAP + g] = r;
            } else {
                int o = atomicAdd(spillc, 1);
                if (o < SPILL_CAP)
                    spill[o] = make_int2((int)(r >> BKT_SH),
                                         (b << BKT_SH) | (int)(r & (BKT_NODES - 1)));
            }
        }
    }
}

// Pass B: one block per bucket; counts + slots tile built in LDS (65KB),
// written out fully coalesced.
__global__ __launch_bounds__(256) void build_kernel(
        const unsigned* __restrict__ rec, const int* __restrict__ gcur,
        int* __restrict__ counts, int* __restrict__ slots,
        int* __restrict__ ovfc, int* __restrict__ ovf) {
    __shared__ int lcnt[BKT_NODES];
    __shared__ int lslots[BKT_NODES * DEG_CAP];   // 64KB
    int b = blockIdx.x;
    for (int i = threadIdx.x; i < BKT_NODES; i += 256) lcnt[i] = 0;
    __syncthreads();
    int n = gcur[b];
    if (n > BKT_CAP) n = BKT_CAP;
    for (int i = threadIdx.x; i < n; i += 256) {
        unsigned r = rec[b * BKT_CAP + i];
        int dlo = (int)(r & (BKT_NODES - 1));
        int src = (int)(r >> BKT_SH);
        int pos = atomicAdd(&lcnt[dlo], 1);
        if (pos < DEG_CAP) {
            lslots[dlo * DEG_CAP + pos] = src;
        } else {
            int o = atomicAdd(ovfc, 1);
            if (o < OVF_CAP) {
                ovf[o * 2] = src;
                ovf[o * 2 + 1] = (b << BKT_SH) | dlo;
            }
        }
    }
    __syncthreads();
    int nodeBase = b << BKT_SH;
    for (int i = threadIdx.x; i < BKT_NODES; i += 256)
        counts[nodeBase + i] = lcnt[i];
    const int4* ls4 = (const int4*)lslots;
    int4* gs4 = (int4*)(slots + nodeBase * DEG_CAP);
    for (int i = threadIdx.x; i < BKT_NODES * DEG_CAP / 4; i += 256)
        gs4[i] = ls4[i];
}

// Rare-path spill fix-up.
__global__ __launch_bounds__(64) void spill_fix_kernel(
        const int2* __restrict__ spill, const int* __restrict__ spillc,
        int* __restrict__ counts, int* __restrict__ slots,
        int* __restrict__ ovfc, int* __restrict__ ovf) {
    int n = *spillc;
    if (n > SPILL_CAP) n = SPILL_CAP;
    int i = blockIdx.x * 64 + threadIdx.x;
    if (i >= n) return;
    int s = spill[i].x;
    int d = spill[i].y;
    int pos = atomicAdd(&counts[d], 1);
    if (pos < DEG_CAP) {
        slots[d * DEG_CAP + pos] = s;
    } else {
        int o = atomicAdd(ovfc, 1);
        if (o < OVF_CAP) { ovf[o * 2] = s; ovf[o * 2 + 1] = d; }
    }
}

// One wave per node; reads xh (rounded bf16), writes the MEAN as hi/lo planes.
__global__ __launch_bounds__(256) void gather_bf_kernel(
        const unsigned short* __restrict__ feat, const int* __restrict__ counts,
        const int* __restrict__ slots,
        unsigned short* __restrict__ mh, unsigned short* __restrict__ ml) {
    int wid = blockIdx.x * 4 + (threadIdx.x >> 6);
    int l = threadIdx.x & 63;
    if (wid >= N_NODES) return;
    int deg = counts[wid];
    int dcap = min(deg, DEG_CAP);
    int ids = slots[wid * DEG_CAP + l];
    const int grp = l >> 4;
    const int fb = (l & 15) * 4;
    float s0 = 0.f, s1 = 0.f, s2 = 0.f, s3 = 0.f;
    int j = 0;
    for (; j + 8 <= dcap; j += 8) {
        int sA = __shfl(ids, j + grp);
        int sB = __shfl(ids, j + 4 + grp);
        uint2 uA = *(const uint2*)(feat + sA * 64 + fb);
        uint2 uB = *(const uint2*)(feat + sB * 64 + fb);
        s0 += bflo(uA.x) + bflo(uB.x);
        s1 += bfhi(uA.x) + bfhi(uB.x);
        s2 += bflo(uA.y) + bflo(uB.y);
        s3 += bfhi(uA.y) + bfhi(uB.y);
    }
    for (; j < dcap; j += 4) {
        int nb = j + grp;
        bool v = nb < dcap;
        int s = __shfl(ids, v ? nb : 0);
        uint2 u = *(const uint2*)(feat + s * 64 + fb);
        if (v) {
            s0 += bflo(u.x);
            s1 += bfhi(u.x);
            s2 += bflo(u.y);
            s3 += bfhi(u.y);
        }
    }
    s0 += __shfl_xor(s0, 16); s0 += __shfl_xor(s0, 32);
    s1 += __shfl_xor(s1, 16); s1 += __shfl_xor(s1, 32);
    s2 += __shfl_xor(s2, 16); s2 += __shfl_xor(s2, 32);
    s3 += __shfl_xor(s3, 16); s3 += __shfl_xor(s3, 32);
    if (l < 16) {
        float inv = 1.0f / fmaxf((float)deg, 1.0f);
        ushort4 oh, ol;
        split_rbf(s0 * inv, oh.x, ol.x);
        split_rbf(s1 * inv, oh.y, ol.y);
        split_rbf(s2 * inv, oh.z, ol.z);
        split_rbf(s3 * inv, oh.w, ol.w);
        *(ushort4*)&mh[wid * 64 + fb] = oh;
        *(ushort4*)&ml[wid * 64 + fb] = ol;
    }
}

// Layer-1 overflow fix-up on hi/lo mean planes. SINGLE block, sequential.
__global__ __launch_bounds__(64) void ovf_mean_fix_kernel(
        const float* __restrict__ x, const int* __restrict__ ovf,
        const int* __restrict__ ovfc, const int* __restrict__ counts,
        unsigned short* __restrict__ mh, unsigned short* __restrict__ ml) {
    int n = *ovfc;
    if (n > OVF_CAP) n = OVF_CAP;
    int t = threadIdx.x;
    for (int idx = 0; idx < n; ++idx) {
        int s = ovf[idx * 2];
        int d = ovf[idx * 2 + 1];
        float inv = 1.0f / fmaxf((float)counts[d], 1.0f);
        float m = bf2f(mh[d * 64 + t]) + bf2f(ml[d * 64 + t])
                + x[s * 64 + t] * inv;
        unsigned short hb, lb;
        split_rbf(m, hb, lb);
        mh[d * 64 + t] = hb;
        ml[d * 64 + t] = lb;
        __syncthreads();
    }
}

// FUSED MLP, 128-row tiles, 8 WAVES (512 thr): wave w owns col-tile c=w.
// Same per-block B-fragment traffic as the 4-wave version (each of the 8
// col-tiles' frags loaded once per block), half the per-wave registers,
// and 2x the resident waves/CU (~24 vs ~12) for latency hiding — the
// counter-identified constraint (Occ 20%, nothing else >17%).
__global__ __launch_bounds__(512) void mlp_fused_kernel(
        const unsigned short* __restrict__ mh, const unsigned short* __restrict__ ml,
        const unsigned short* __restrict__ xh, const unsigned short* __restrict__ xl,
        const short* __restrict__ Bf1, const float* __restrict__ b1,
        const short* __restrict__ Bf2, const float* __restrict__ b2,
        unsigned short* __restrict__ p_bf, float* __restrict__ q) {
    __shared__ unsigned short h_lds[128][136];   // 34816 B
    const int w = threadIdx.x >> 6;      // 0..7 = col-tile
    const int l = threadIdx.x & 63;
    const int lane15 = l & 15;
    const int quad = l >> 4;
    const int rowBase = blockIdx.x * 128;

    // ---- phase 1: layer 1, B-stationary, 3-MFMA hi/lo split ----
    {
        bf16x8 bh[4], bl[4];
#pragma unroll
        for (int kc = 0; kc < 4; ++kc) {
            const short* bp = Bf1 + ((w * 4 + kc) * 2) * 512 + l * 8;
            bh[kc] = *(const bf16x8*)bp;
            bl[kc] = *(const bf16x8*)(bp + 512);
        }
        const float bias = b1[w * 16 + lane15];

#pragma unroll
        for (int rt = 0; rt < 8; ++rt) {
            const int row = rowBase + rt * 16 + lane15;
            const bool rv = row < N_NODES;
            const bf16x8 zz = {0, 0, 0, 0, 0, 0, 0, 0};

            bf16x8 ah[4], al[4];
#pragma unroll
            for (int kc = 0; kc < 4; ++kc) {
                if (rv) {
                    const int off = (kc < 2)
                        ? row * 64 + kc * 32 + quad * 8
                        : row * 64 + (kc - 2) * 32 + quad * 8;
                    const unsigned short* ph = (kc < 2) ? (mh + off) : (xh + off);
                    const unsigned short* pl = (kc < 2) ? (ml + off) : (xl + off);
                    ah[kc] = *(const bf16x8*)ph;
                    al[kc] = *(const bf16x8*)pl;
                } else {
                    ah[kc] = zz;
                    al[kc] = zz;
                }
            }

            f32x4 acc = (f32x4){0.f, 0.f, 0.f, 0.f};
#pragma unroll
            for (int kc = 0; kc < 4; ++kc) {
                acc = __builtin_amdgcn_mfma_f32_16x16x32_bf16(ah[kc], bh[kc], acc, 0, 0, 0);
                acc = __builtin_amdgcn_mfma_f32_16x16x32_bf16(al[kc], bh[kc], acc, 0, 0, 0);
                acc = __builtin_amdgcn_mfma_f32_16x16x32_bf16(ah[kc], bl[kc], acc, 0, 0, 0);
            }

            const int rloc = rt * 16 + quad * 4;
            const int col = w * 16 + lane15;
#pragma unroll
            for (int i = 0; i < 4; ++i)
                h_lds[rloc + i][col] = f2bf(fmaxf(acc[i] + bias, 0.f));
        }
    }
    __syncthreads();

    // ---- phase 2: layer 2 from LDS (A = bf16, W2 keeps hi/lo split) ----
    {
        bf16x8 bh[4], bl[4];
#pragma unroll
        for (int kc = 0; kc < 4; ++kc) {
            const short* bp = Bf2 + ((w * 4 + kc) * 2) * 512 + l * 8;
            bh[kc] = *(const bf16x8*)bp;
            bl[kc] = *(const bf16x8*)(bp + 512);
        }
        const float bias = (w >= 4) ? b2[(w - 4) * 16 + lane15] : 0.f;

#pragma unroll
        for (int rt = 0; rt < 8; ++rt) {
            bf16x8 ah[4];
#pragma unroll
            for (int kc = 0; kc < 4; ++kc)
                ah[kc] = *(const bf16x8*)&h_lds[rt * 16 + lane15][kc * 32 + quad * 8];

            f32x4 acc = (f32x4){0.f, 0.f, 0.f, 0.f};
#pragma unroll
            for (int kc = 0; kc < 4; ++kc) {
                acc = __builtin_amdgcn_mfma_f32_16x16x32_bf16(ah[kc], bh[kc], acc, 0, 0, 0);
                acc = __builtin_amdgcn_mfma_f32_16x16x32_bf16(ah[kc], bl[kc], acc, 0, 0, 0);
            }

            const int rb = rowBase + rt * 16 + quad * 4;
            if (w < 4) {
                const int col = w * 16 + lane15;
#pragma unroll
                for (int i = 0; i < 4; ++i) {
                    int r = rb + i;
                    if (r < N_NODES)
                        p_bf[r * 64 + col] = f2bf(acc[i]);
                }
            } else {
                const int col = (w - 4) * 16 + lane15;
#pragma unroll
                for (int i = 0; i < 4; ++i) {
                    int r = rb + i;
                    if (r < N_NODES)
                        q[r * 64 + col] = acc[i] + bias;
                }
            }
        }
    }
}

// Fused layer-2 aggregation + epilogue: out = mean(p_bf[nbrs]) + q
__global__ __launch_bounds__(256) void gather_final_kernel(
        const unsigned short* __restrict__ p, const int* __restrict__ counts,
        const int* __restrict__ slots, const float* __restrict__ q,
        float* __restrict__ out) {
    int wid = blockIdx.x * 4 + (threadIdx.x >> 6);
    int l = threadIdx.x & 63;
    if (wid >= N_NODES) return;
    int deg = counts[wid];
    int dcap = min(deg, DEG_CAP);
    int ids = slots[wid * DEG_CAP + l];
    const int grp = l >> 4;
    const int fb = (l & 15) * 4;
    float s0 = 0.f, s1 = 0.f, s2 = 0.f, s3 = 0.f;
    int j = 0;
    for (; j + 8 <= dcap; j += 8) {
        int sA = __shfl(ids, j + grp);
        int sB = __shfl(ids, j + 4 + grp);
        uint2 uA = *(const uint2*)(p + sA * 64 + fb);
        uint2 uB = *(const uint2*)(p + sB * 64 + fb);
        s0 += bflo(uA.x) + bflo(uB.x);
        s1 += bfhi(uA.x) + bfhi(uB.x);
        s2 += bflo(uA.y) + bflo(uB.y);
        s3 += bfhi(uA.y) + bfhi(uB.y);
    }
    for (; j < dcap; j += 4) {
        int nb = j + grp;
        bool v = nb < dcap;
        int s = __shfl(ids, v ? nb : 0);
        uint2 u = *(const uint2*)(p + s * 64 + fb);
        if (v) {
            s0 += bflo(u.x);
            s1 += bfhi(u.x);
            s2 += bflo(u.y);
            s3 += bfhi(u.y);
        }
    }
    s0 += __shfl_xor(s0, 16); s0 += __shfl_xor(s0, 32);
    s1 += __shfl_xor(s1, 16); s1 += __shfl_xor(s1, 32);
    s2 += __shfl_xor(s2, 16); s2 += __shfl_xor(s2, 32);
    s3 += __shfl_xor(s3, 16); s3 += __shfl_xor(s3, 32);
    if (l < 16) {
        float inv = 1.0f / fmaxf((float)deg, 1.0f);
        float4 qv = *(const float4*)&q[wid * 64 + fb];
        *(float4*)&out[wid * 64 + fb] =
            make_float4(s0 * inv + qv.x, s1 * inv + qv.y,
                        s2 * inv + qv.z, s3 * inv + qv.w);
    }
}

// Layer-2 overflow fix-up (additive).
__global__ __launch_bounds__(64) void ovf_fixup_kernel(
        const unsigned short* __restrict__ p, const int* __restrict__ ovf,
        const int* __restrict__ ovfc, const int* __restrict__ counts,
        float* __restrict__ out) {
    int n = *ovfc;
    if (n > OVF_CAP) n = OVF_CAP;
    for (int idx = blockIdx.x; idx < n; idx += gridDim.x) {
        int s = ovf[idx * 2];
        int d = ovf[idx * 2 + 1];
        float inv = 1.0f / fmaxf((float)counts[d], 1.0f);
        atomicAdd(&out[d * 64 + threadIdx.x],
                  bf2f(p[s * 64 + threadIdx.x]) * inv);
    }
}

extern "C" void kernel_launch(void* const* d_in, const int* in_sizes, int n_in,
                              void* d_out, int out_size, void* d_ws, size_t ws_size,
                              hipStream_t stream) {
    const float* x   = (const float*)d_in[0];
    const float* W1l = (const float*)d_in[1];
    const float* W1r = (const float*)d_in[2];
    const float* b1  = (const float*)d_in[3];
    const float* W2l = (const float*)d_in[4];
    const float* W2r = (const float*)d_in[5];
    const float* b2  = (const float*)d_in[6];
    const int*   ei  = (const int*)d_in[7];

    int*   wsi      = (int*)d_ws;
    float* wsf      = (float*)d_ws;
    int*   counts   = wsi;
    int*   ovfc     = wsi + 100352;
    int*   spillc   = wsi + 100353;
    int*   gcur     = wsi + 100416;
    int*   ovf      = wsi + 100928;
    int2*  spill    = (int2*)(wsi + 109120);
    short* Bf1      = (short*)(wsi + 117312);
    short* Bf2      = (short*)(wsi + 133696);
    int*   slots    = wsi + 150080;
    unsigned* rec   = (unsigned*)(wsi + 6572608);
    unsigned short* xh = (unsigned short*)(wsi + 8178240);
    unsigned short* xl = (unsigned short*)(wsi + 11378240);
    unsigned short* mh = (unsigned short*)(wsi + 14578240);
    unsigned short* ml = (unsigned short*)(wsi + 17778240);
    unsigned short* p_bf = (unsigned short*)(wsi + 20978240);
    float* q        = wsf + 24178240;
    float* out      = (float*)d_out;

    prep_kernel<<<(N_NODES * 16 + 255) / 256, 256, 0, stream>>>(
        (const float4*)x, (ushort4*)xh, (ushort4*)xl, W1l, W1r, W2l, W2r,
        Bf1, Bf2, (int4*)gcur, ovfc, spillc);

    // indexing: LDS-binned two-pass
    bin_kernel<<<(N_EDGES + BIN_CHUNK - 1) / BIN_CHUNK, 256, 0, stream>>>(
        ei, rec, gcur, spillc, spill);
    build_kernel<<<NBKT, 256, 0, stream>>>(rec, gcur, counts, slots, ovfc, ovf);
    spill_fix_kernel<<<SPILL_CAP / 64, 64, 0, stream>>>(
        spill, spillc, counts, slots, ovfc, ovf);

    // layer-1 aggregation -> mean hi/lo planes, + overflow fix
    gather_bf_kernel<<<(N_NODES + 3) / 4, 256, 0, stream>>>(
        xh, counts, slots, mh, ml);
    ovf_mean_fix_kernel<<<1, 64, 0, stream>>>(x, ovf, ovfc, counts, mh, ml);

    // fused MLP: h (LDS) -> p_bf, q in one pass (128 rows, 8 waves)
    mlp_fused_kernel<<<(N_NODES + 127) / 128, 512, 0, stream>>>(
        mh, ml, xh, xl, Bf1, b1, Bf2, b2, p_bf, q);

    // fused layer-2 aggregation + epilogue, then overflow fix-up
    gather_final_kernel<<<(N_NODES + 3) / 4, 256, 0, stream>>>(
        p_bf, counts, slots, q, out);
    ovf_fixup_kernel<<<64, 64, 0, stream>>>(p_bf, ovf, ovfc, counts, out);
}

// Round 10
// 228.491 us; speedup vs baseline: 1.1166x; 1.1166x over previous
//
#include <hip/hip_runtime.h>

#define N_NODES 100000
#define N_EDGES 1000000
#define DEG_CAP 64
#define OVF_CAP 4096
#define SPILL_CAP 4096

// binning geometry
#define BKT_SH 8
#define BKT_NODES 256            // nodes per bucket
#define NBKT 392                 // 392*256 = 100352 >= N_NODES
#define BKT_CAP 4096             // record capacity per bucket (mean ~2551)
#define BIN_CHUNK 4096           // edges per bin block
#define FIFO_CAP 32              // LDS fifo depth per bucket (mean ~10.4)

typedef __attribute__((ext_vector_type(8))) short bf16x8;
typedef __attribute__((ext_vector_type(4))) float f32x4;

__device__ __forceinline__ unsigned short f2bf(float f) {
    unsigned u = __float_as_uint(f);
    return (unsigned short)((u + 0x7FFF + ((u >> 16) & 1)) >> 16);
}
__device__ __forceinline__ float bf2f(unsigned short b) {
    return __uint_as_float(((unsigned)b) << 16);
}
__device__ __forceinline__ float bflo(unsigned u) {   // low bf16 of a dword
    return __uint_as_float(u << 16);
}
__device__ __forceinline__ float bfhi(unsigned u) {   // high bf16 of a dword
    return __uint_as_float(u & 0xffff0000u);
}
// rounded hi + rounded residual lo: hi is BIT-IDENTICAL to f2bf(f) (the
// gather source), and hi+lo reconstructs f to ~2^-17 relative.
__device__ __forceinline__ void split_rbf(float f, unsigned short& ho,
                                          unsigned short& lo) {
    unsigned short hb = f2bf(f);
    ho = hb;
    lo = f2bf(f - bf2f(hb));
}

// ws layout (4B units) — AUDITED (u16 plane = N*64 u16 = 3,200,000 dwords):
//   counts : [0, 100352)
//   ovfc 100352 ; spillc 100353
//   gcur   : [100416, 100928)
//   ovf    : [100928, 109120)
//   spill  : [109120, 117312)
//   Bf1    : s16 [117312, 133696)
//   Bf2    : s16 [133696, 150080)
//   slots  : [150080, 6572608)        100352*64 dwords
//   rec    : u32 [6572608, 8178240)   392*4096
//   xh     : u16 [8178240,  11378240) 3.2M dwords = 6.4M u16
//   xl     : u16 [11378240, 14578240)
//   mh     : u16 [14578240, 17778240)
//   ml     : u16 [17778240, 20978240)
//   p_bf   : u16 [20978240, 24178240)
//   q      : f32 [24178240, 30578240)
// total 30,578,240 dwords = 122.3 MB

// Merged init + weight-split + x -> rounded-hi/residual-lo planes.
__global__ __launch_bounds__(256) void prep_kernel(
        const float4* __restrict__ x4,
        ushort4* __restrict__ xh4, ushort4* __restrict__ xl4,
        const float* __restrict__ W1l, const float* __restrict__ W1r,
        const float* __restrict__ W2l, const float* __restrict__ W2r,
        short* __restrict__ Bf1, short* __restrict__ Bf2,
        int4* __restrict__ gcur4, int* __restrict__ ovfc,
        int* __restrict__ spillc) {
    int i = blockIdx.x * blockDim.x + threadIdx.x;
    if (i < 128) gcur4[i] = make_int4(0, 0, 0, 0);
    if (i == 0) { *ovfc = 0; *spillc = 0; }
    if (i < 32768) {
        int g = i >> 14;
        int e = i & 16383;
        int k = e >> 7;
        int n = e & 127;
        float v;
        if (g == 0) v = (k < 64) ? W1l[k * 128 + n] : W1r[(k - 64) * 128 + n];
        else        v = (n < 64) ? W2l[k * 64 + n]  : W2r[k * 64 + (n - 64)];
        unsigned short hb, lb;
        split_rbf(v, hb, lb);
        int c = n >> 4, kc = k >> 5;
        int lane = (((k >> 3) & 3) << 4) | (n & 15);
        int j = k & 7;
        short* base = g ? Bf2 : Bf1;
        base[((c * 4 + kc) * 2 + 0) * 512 + lane * 8 + j] = (short)hb;
        base[((c * 4 + kc) * 2 + 1) * 512 + lane * 8 + j] = (short)lb;
    }
    if (i < N_NODES * 16) {
        float4 v = x4[i];
        ushort4 oh, ol;
        split_rbf(v.x, oh.x, ol.x);
        split_rbf(v.y, oh.y, ol.y);
        split_rbf(v.z, oh.z, ol.z);
        split_rbf(v.w, oh.w, ol.w);
        xh4[i] = oh;
        xl4[i] = ol;
    }
}

// Pass A: bin edges into 392 dst-range buckets via LDS FIFOs.
__global__ __launch_bounds__(256) void bin_kernel(
        const int* __restrict__ ei, unsigned* __restrict__ rec,
        int* __restrict__ gcur, int* __restrict__ spillc,
        int2* __restrict__ spill) {
    __shared__ int lcnt[NBKT];
    __shared__ unsigned fifo[NBKT * FIFO_CAP];   // 50KB
    for (int i = threadIdx.x; i < NBKT; i += 256) lcnt[i] = 0;
    __syncthreads();
    int base = blockIdx.x * BIN_CHUNK;
    int end = base + BIN_CHUNK;
    if (end > N_EDGES) end = N_EDGES;
    for (int e = base + threadIdx.x; e < end; e += 256) {
        int s = ei[e];
        int d = ei[N_EDGES + e];
        int b = d >> BKT_SH;
        unsigned r = ((unsigned)s << BKT_SH) | (unsigned)(d & (BKT_NODES - 1));
        int pos = atomicAdd(&lcnt[b], 1);
        if (pos < FIFO_CAP) {
            fifo[b * FIFO_CAP + pos] = r;
        } else {
            int o = atomicAdd(spillc, 1);
            if (o < SPILL_CAP) spill[o] = make_int2(s, d);
        }
    }
    __syncthreads();
    for (int b = threadIdx.x; b < NBKT; b += 256) {
        int cnt = lcnt[b];
        if (cnt > FIFO_CAP) cnt = FIFO_CAP;
        if (cnt == 0) continue;
        int gb = atomicAdd(&gcur[b], cnt);
        for (int k = 0; k < cnt; ++k) {
            int g = gb + k;
            unsigned r = fifo[b * FIFO_CAP + k];
            if (g < BKT_CAP) {
                rec[b * BKT_CAP + g] = r;
            } else {
                int o = atomicAdd(spillc, 1);
                if (o < SPILL_CAP)
                    spill[o] = make_int2((int)(r >> BKT_SH),
                                         (b << BKT_SH) | (int)(r & (BKT_NODES - 1)));
            }
        }
    }
}

// Pass B: one block per bucket; counts + slots tile built in LDS (65KB),
// written out fully coalesced. Spill entries (rare path, ~always 0) are
// handled inline: each block scans the tiny spill list for its own
// bucket range — this deletes the separate spill_fix launch.
__global__ __launch_bounds__(256) void build_kernel(
        const unsigned* __restrict__ rec, const int* __restrict__ gcur,
        const int2* __restrict__ spill, const int* __restrict__ spillc,
        int* __restrict__ counts, int* __restrict__ slots,
        int* __restrict__ ovfc, int* __restrict__ ovf) {
    __shared__ int lcnt[BKT_NODES];
    __shared__ int lslots[BKT_NODES * DEG_CAP];   // 64KB
    int b = blockIdx.x;
    for (int i = threadIdx.x; i < BKT_NODES; i += 256) lcnt[i] = 0;
    __syncthreads();
    int n = gcur[b];
    if (n > BKT_CAP) n = BKT_CAP;
    for (int i = threadIdx.x; i < n; i += 256) {
        unsigned r = rec[b * BKT_CAP + i];
        int dlo = (int)(r & (BKT_NODES - 1));
        int src = (int)(r >> BKT_SH);
        int pos = atomicAdd(&lcnt[dlo], 1);
        if (pos < DEG_CAP) {
            lslots[dlo * DEG_CAP + pos] = src;
        } else {
            int o = atomicAdd(ovfc, 1);
            if (o < OVF_CAP) {
                ovf[o * 2] = src;
                ovf[o * 2 + 1] = (b << BKT_SH) | dlo;
            }
        }
    }
    // inline spill handling (usually ns == 0)
    int ns = *spillc;
    if (ns > SPILL_CAP) ns = SPILL_CAP;
    for (int i = threadIdx.x; i < ns; i += 256) {
        int2 e = spill[i];
        if ((e.y >> BKT_SH) == b) {
            int dlo = e.y & (BKT_NODES - 1);
            int pos = atomicAdd(&lcnt[dlo], 1);
            if (pos < DEG_CAP) {
                lslots[dlo * DEG_CAP + pos] = e.x;
            } else {
                int o = atomicAdd(ovfc, 1);
                if (o < OVF_CAP) { ovf[o * 2] = e.x; ovf[o * 2 + 1] = e.y; }
            }
        }
    }
    __syncthreads();
    int nodeBase = b << BKT_SH;
    for (int i = threadIdx.x; i < BKT_NODES; i += 256)
        counts[nodeBase + i] = lcnt[i];
    const int4* ls4 = (const int4*)lslots;
    int4* gs4 = (int4*)(slots + nodeBase * DEG_CAP);
    for (int i = threadIdx.x; i < BKT_NODES * DEG_CAP / 4; i += 256)
        gs4[i] = ls4[i];
}

// One wave per node; reads xh (rounded bf16), writes the MEAN as hi/lo planes.
__global__ __launch_bounds__(256) void gather_bf_kernel(
        const unsigned short* __restrict__ feat, const int* __restrict__ counts,
        const int* __restrict__ slots,
        unsigned short* __restrict__ mh, unsigned short* __restrict__ ml) {
    int wid = blockIdx.x * 4 + (threadIdx.x >> 6);
    int l = threadIdx.x & 63;
    if (wid >= N_NODES) return;
    int deg = counts[wid];
    int dcap = min(deg, DEG_CAP);
    int ids = slots[wid * DEG_CAP + l];
    const int grp = l >> 4;
    const int fb = (l & 15) * 4;
    float s0 = 0.f, s1 = 0.f, s2 = 0.f, s3 = 0.f;
    int j = 0;
    for (; j + 8 <= dcap; j += 8) {
        int sA = __shfl(ids, j + grp);
        int sB = __shfl(ids, j + 4 + grp);
        uint2 uA = *(const uint2*)(feat + sA * 64 + fb);
        uint2 uB = *(const uint2*)(feat + sB * 64 + fb);
        s0 += bflo(uA.x) + bflo(uB.x);
        s1 += bfhi(uA.x) + bfhi(uB.x);
        s2 += bflo(uA.y) + bflo(uB.y);
        s3 += bfhi(uA.y) + bfhi(uB.y);
    }
    for (; j < dcap; j += 4) {
        int nb = j + grp;
        bool v = nb < dcap;
        int s = __shfl(ids, v ? nb : 0);
        uint2 u = *(const uint2*)(feat + s * 64 + fb);
        if (v) {
            s0 += bflo(u.x);
            s1 += bfhi(u.x);
            s2 += bflo(u.y);
            s3 += bfhi(u.y);
        }
    }
    s0 += __shfl_xor(s0, 16); s0 += __shfl_xor(s0, 32);
    s1 += __shfl_xor(s1, 16); s1 += __shfl_xor(s1, 32);
    s2 += __shfl_xor(s2, 16); s2 += __shfl_xor(s2, 32);
    s3 += __shfl_xor(s3, 16); s3 += __shfl_xor(s3, 32);
    if (l < 16) {
        float inv = 1.0f / fmaxf((float)deg, 1.0f);
        ushort4 oh, ol;
        split_rbf(s0 * inv, oh.x, ol.x);
        split_rbf(s1 * inv, oh.y, ol.y);
        split_rbf(s2 * inv, oh.z, ol.z);
        split_rbf(s3 * inv, oh.w, ol.w);
        *(ushort4*)&mh[wid * 64 + fb] = oh;
        *(ushort4*)&ml[wid * 64 + fb] = ol;
    }
}

// FUSED MLP, 128-row tiles, 4 waves × 2 col-tiles (round-8 config — the
// measured optimum; 64-row and 8-wave variants both measured worse).
// Preamble: layer-1 overflow fix for rows in this block's range (deletes
// the ovf_mean_fix launch; n is ~always 0). Phase-1 A operands load
// directly from pre-split hi/lo planes; h staged in LDS as bf16.
__global__ __launch_bounds__(256) void mlp_fused_kernel(
        const unsigned short* __restrict__ mh, const unsigned short* __restrict__ ml,
        const unsigned short* __restrict__ xh, const unsigned short* __restrict__ xl,
        const float* __restrict__ x,
        const short* __restrict__ Bf1, const float* __restrict__ b1,
        const short* __restrict__ Bf2, const float* __restrict__ b2,
        const int* __restrict__ ovf, const int* __restrict__ ovfc,
        const int* __restrict__ counts,
        unsigned short* __restrict__ p_bf_out, float* __restrict__ q) {
    __shared__ unsigned short h_lds[128][136];   // 34816 B
    const int w = threadIdx.x >> 6;
    const int l = threadIdx.x & 63;
    const int lane15 = l & 15;
    const int quad = l >> 4;
    const int rowBase = blockIdx.x * 128;

    // ---- preamble: layer-1 overflow fix for this block's rows ----
    {
        int n = *ovfc;
        if (n > OVF_CAP) n = OVF_CAP;
        if (n > 0) {
            for (int idx = 0; idx < n; ++idx) {
                int d = ovf[idx * 2 + 1];
                if (d >= rowBase && d < rowBase + 128) {
                    if (threadIdx.x < 64) {
                        int s = ovf[idx * 2];
                        int t = threadIdx.x;
                        float inv = 1.0f / fmaxf((float)counts[d], 1.0f);
                        float m = bf2f(mh[d * 64 + t]) + bf2f(ml[d * 64 + t])
                                + x[s * 64 + t] * inv;
                        unsigned short hb, lb;
                        split_rbf(m, hb, lb);
                        // const_cast is safe: ws region, this block owns row d
                        ((unsigned short*)mh)[d * 64 + t] = hb;
                        ((unsigned short*)ml)[d * 64 + t] = lb;
                    }
                    __syncthreads();   // order RMW chains on repeated d
                }
            }
            __syncthreads();
        }
    }

    // ---- phase 1: layer 1, B-stationary, 3-MFMA hi/lo split ----
    {
        bf16x8 bh[2][4], bl[2][4];
#pragma unroll
        for (int ci = 0; ci < 2; ++ci) {
            const int c = 2 * w + ci;
#pragma unroll
            for (int kc = 0; kc < 4; ++kc) {
                const short* bp = Bf1 + ((c * 4 + kc) * 2) * 512 + l * 8;
                bh[ci][kc] = *(const bf16x8*)bp;
                bl[ci][kc] = *(const bf16x8*)(bp + 512);
            }
        }
        float bias[2];
#pragma unroll
        for (int ci = 0; ci < 2; ++ci) bias[ci] = b1[(2 * w + ci) * 16 + lane15];

#pragma unroll
        for (int rt = 0; rt < 8; ++rt) {
            const int row = rowBase + rt * 16 + lane15;
            const bool rv = row < N_NODES;
            const bf16x8 zz = {0, 0, 0, 0, 0, 0, 0, 0};

            bf16x8 ah[4], al[4];
#pragma unroll
            for (int kc = 0; kc < 4; ++kc) {
                if (rv) {
                    const int off = (kc < 2)
                        ? row * 64 + kc * 32 + quad * 8
                        : row * 64 + (kc - 2) * 32 + quad * 8;
                    const unsigned short* ph = (kc < 2) ? (mh + off) : (xh + off);
                    const unsigned short* pl = (kc < 2) ? (ml + off) : (xl + off);
                    ah[kc] = *(const bf16x8*)ph;
                    al[kc] = *(const bf16x8*)pl;
                } else {
                    ah[kc] = zz;
                    al[kc] = zz;
                }
            }

            f32x4 acc[2] = {(f32x4){0.f, 0.f, 0.f, 0.f}, (f32x4){0.f, 0.f, 0.f, 0.f}};
#pragma unroll
            for (int kc = 0; kc < 4; ++kc) {
#pragma unroll
                for (int ci = 0; ci < 2; ++ci) {
                    acc[ci] = __builtin_amdgcn_mfma_f32_16x16x32_bf16(ah[kc], bh[ci][kc], acc[ci], 0, 0, 0);
                    acc[ci] = __builtin_amdgcn_mfma_f32_16x16x32_bf16(al[kc], bh[ci][kc], acc[ci], 0, 0, 0);
                    acc[ci] = __builtin_amdgcn_mfma_f32_16x16x32_bf16(ah[kc], bl[ci][kc], acc[ci], 0, 0, 0);
                }
            }

            const int rloc = rt * 16 + quad * 4;
#pragma unroll
            for (int ci = 0; ci < 2; ++ci) {
                const int col = (2 * w + ci) * 16 + lane15;
#pragma unroll
                for (int i = 0; i < 4; ++i)
                    h_lds[rloc + i][col] =
                        f2bf(fmaxf(acc[ci][i] + bias[ci], 0.f));
            }
        }
    }
    __syncthreads();

    // ---- phase 2: layer 2 from LDS (A = bf16, W2 keeps hi/lo split) ----
    {
        bf16x8 bh[2][4], bl[2][4];
#pragma unroll
        for (int ci = 0; ci < 2; ++ci) {
            const int c = 2 * w + ci;
#pragma unroll
            for (int kc = 0; kc < 4; ++kc) {
                const short* bp = Bf2 + ((c * 4 + kc) * 2) * 512 + l * 8;
                bh[ci][kc] = *(const bf16x8*)bp;
                bl[ci][kc] = *(const bf16x8*)(bp + 512);
            }
        }
        float bias[2];
#pragma unroll
        for (int ci = 0; ci < 2; ++ci) {
            const int c = 2 * w + ci;
            bias[ci] = (c >= 4) ? b2[(c - 4) * 16 + lane15] : 0.f;
        }

#pragma unroll
        for (int rt = 0; rt < 8; ++rt) {
            bf16x8 ah[4];
#pragma unroll
            for (int kc = 0; kc < 4; ++kc)
                ah[kc] = *(const bf16x8*)&h_lds[rt * 16 + lane15][kc * 32 + quad * 8];

            f32x4 acc[2] = {(f32x4){0.f, 0.f, 0.f, 0.f}, (f32x4){0.f, 0.f, 0.f, 0.f}};
#pragma unroll
            for (int kc = 0; kc < 4; ++kc) {
#pragma unroll
                for (int ci = 0; ci < 2; ++ci) {
                    acc[ci] = __builtin_amdgcn_mfma_f32_16x16x32_bf16(ah[kc], bh[ci][kc], acc[ci], 0, 0, 0);
                    acc[ci] = __builtin_amdgcn_mfma_f32_16x16x32_bf16(ah[kc], bl[ci][kc], acc[ci], 0, 0, 0);
                }
            }

            const int rb = rowBase + rt * 16 + quad * 4;
#pragma unroll
            for (int ci = 0; ci < 2; ++ci) {
                const int c = 2 * w + ci;
                if (c < 4) {
#pragma unroll
                    for (int i = 0; i < 4; ++i) {
                        int r = rb + i;
                        if (r < N_NODES)
                            p_bf_out[r * 64 + c * 16 + lane15] = f2bf(acc[ci][i]);
                    }
                } else {
#pragma unroll
                    for (int i = 0; i < 4; ++i) {
                        int r = rb + i;
                        if (r < N_NODES)
                            q[r * 64 + (c - 4) * 16 + lane15] = acc[ci][i] + bias[ci];
                    }
                }
            }
        }
    }
}

// Fused layer-2 aggregation + epilogue: out = mean(p_bf[nbrs]) + q.
// Layer-2 overflow entries are added inline (deletes the ovf_fixup launch).
__global__ __launch_bounds__(256) void gather_final_kernel(
        const unsigned short* __restrict__ p, const int* __restrict__ counts,
        const int* __restrict__ slots, const float* __restrict__ q,
        const int* __restrict__ ovf, const int* __restrict__ ovfc,
        float* __restrict__ out) {
    int wid = blockIdx.x * 4 + (threadIdx.x >> 6);
    int l = threadIdx.x & 63;
    if (wid >= N_NODES) return;
    int deg = counts[wid];
    int dcap = min(deg, DEG_CAP);
    int ids = slots[wid * DEG_CAP + l];
    const int grp = l >> 4;
    const int fb = (l & 15) * 4;
    float s0 = 0.f, s1 = 0.f, s2 = 0.f, s3 = 0.f;
    int j = 0;
    for (; j + 8 <= dcap; j += 8) {
        int sA = __shfl(ids, j + grp);
        int sB = __shfl(ids, j + 4 + grp);
        uint2 uA = *(const uint2*)(p + sA * 64 + fb);
        uint2 uB = *(const uint2*)(p + sB * 64 + fb);
        s0 += bflo(uA.x) + bflo(uB.x);
        s1 += bfhi(uA.x) + bfhi(uB.x);
        s2 += bflo(uA.y) + bflo(uB.y);
        s3 += bfhi(uA.y) + bfhi(uB.y);
    }
    for (; j < dcap; j += 4) {
        int nb = j + grp;
        bool v = nb < dcap;
        int s = __shfl(ids, v ? nb : 0);
        uint2 u = *(const uint2*)(p + s * 64 + fb);
        if (v) {
            s0 += bflo(u.x);
            s1 += bfhi(u.x);
            s2 += bflo(u.y);
            s3 += bfhi(u.y);
        }
    }
    s0 += __shfl_xor(s0, 16); s0 += __shfl_xor(s0, 32);
    s1 += __shfl_xor(s1, 16); s1 += __shfl_xor(s1, 32);
    s2 += __shfl_xor(s2, 16); s2 += __shfl_xor(s2, 32);
    s3 += __shfl_xor(s3, 16); s3 += __shfl_xor(s3, 32);
    if (l < 16) {
        // inline layer-2 overflow additions (n is ~always 0)
        int n = *ovfc;
        if (n > OVF_CAP) n = OVF_CAP;
        for (int idx = 0; idx < n; ++idx) {
            if (ovf[idx * 2 + 1] == wid) {
                int s = ovf[idx * 2];
                uint2 u = *(const uint2*)(p + s * 64 + fb);
                s0 += bflo(u.x);
                s1 += bfhi(u.x);
                s2 += bflo(u.y);
                s3 += bfhi(u.y);
            }
        }
        float inv = 1.0f / fmaxf((float)deg, 1.0f);
        float4 qv = *(const float4*)&q[wid * 64 + fb];
        *(float4*)&out[wid * 64 + fb] =
            make_float4(s0 * inv + qv.x, s1 * inv + qv.y,
                        s2 * inv + qv.z, s3 * inv + qv.w);
    }
}

extern "C" void kernel_launch(void* const* d_in, const int* in_sizes, int n_in,
                              void* d_out, int out_size, void* d_ws, size_t ws_size,
                              hipStream_t stream) {
    const float* x   = (const float*)d_in[0];
    const float* W1l = (const float*)d_in[1];
    const float* W1r = (const float*)d_in[2];
    const float* b1  = (const float*)d_in[3];
    const float* W2l = (const float*)d_in[4];
    const float* W2r = (const float*)d_in[5];
    const float* b2  = (const float*)d_in[6];
    const int*   ei  = (const int*)d_in[7];

    int*   wsi      = (int*)d_ws;
    float* wsf      = (float*)d_ws;
    int*   counts   = wsi;
    int*   ovfc     = wsi + 100352;
    int*   spillc   = wsi + 100353;
    int*   gcur     = wsi + 100416;
    int*   ovf      = wsi + 100928;
    int2*  spill    = (int2*)(wsi + 109120);
    short* Bf1      = (short*)(wsi + 117312);
    short* Bf2      = (short*)(wsi + 133696);
    int*   slots    = wsi + 150080;
    unsigned* rec   = (unsigned*)(wsi + 6572608);
    unsigned short* xh = (unsigned short*)(wsi + 8178240);
    unsigned short* xl = (unsigned short*)(wsi + 11378240);
    unsigned short* mh = (unsigned short*)(wsi + 14578240);
    unsigned short* ml = (unsigned short*)(wsi + 17778240);
    unsigned short* p_bf = (unsigned short*)(wsi + 20978240);
    float* q        = wsf + 24178240;
    float* out      = (float*)d_out;

    prep_kernel<<<(N_NODES * 16 + 255) / 256, 256, 0, stream>>>(
        (const float4*)x, (ushort4*)xh, (ushort4*)xl, W1l, W1r, W2l, W2r,
        Bf1, Bf2, (int4*)gcur, ovfc, spillc);

    // indexing: LDS-binned two-pass (spill handled inside build)
    bin_kernel<<<(N_EDGES + BIN_CHUNK - 1) / BIN_CHUNK, 256, 0, stream>>>(
        ei, rec, gcur, spillc, spill);
    build_kernel<<<NBKT, 256, 0, stream>>>(
        rec, gcur, spill, spillc, counts, slots, ovfc, ovf);

    // layer-1 aggregation -> mean hi/lo planes
    gather_bf_kernel<<<(N_NODES + 3) / 4, 256, 0, stream>>>(
        xh, counts, slots, mh, ml);

    // fused MLP (ovf preamble inside): h (LDS) -> p_bf, q
    mlp_fused_kernel<<<(N_NODES + 127) / 128, 256, 0, stream>>>(
        mh, ml, xh, xl, x, Bf1, b1, Bf2, b2, ovf, ovfc, counts, p_bf, q);

    // fused layer-2 aggregation + epilogue (ovf additions inside)
    gather_final_kernel<<<(N_NODES + 3) / 4, 256, 0, stream>>>(
        p_bf, counts, slots, q, ovf, ovfc, out);
}

// Round 11
// 215.202 us; speedup vs baseline: 1.1855x; 1.0618x over previous
//
#include <hip/hip_runtime.h>

#define N_NODES 100000
#define N_EDGES 1000000
#define DEG_CAP 64
#define OVF_CAP 4096
#define SPILL_CAP 4096

// binning geometry
#define BKT_SH 8
#define BKT_NODES 256            // nodes per bucket
#define NBKT 392                 // 392*256 = 100352 >= N_NODES
#define BKT_CAP 4096             // record capacity per bucket (mean ~2551)
#define BIN_CHUNK 4096           // edges per bin block
#define FIFO_CAP 32              // LDS fifo depth per bucket (mean ~10.4)

typedef __attribute__((ext_vector_type(8))) short bf16x8;
typedef __attribute__((ext_vector_type(4))) float f32x4;

__device__ __forceinline__ unsigned short f2bf(float f) {
    unsigned u = __float_as_uint(f);
    return (unsigned short)((u + 0x7FFF + ((u >> 16) & 1)) >> 16);
}
__device__ __forceinline__ float bf2f(unsigned short b) {
    return __uint_as_float(((unsigned)b) << 16);
}
__device__ __forceinline__ float bflo(unsigned u) {   // low bf16 of a dword
    return __uint_as_float(u << 16);
}
__device__ __forceinline__ float bfhi(unsigned u) {   // high bf16 of a dword
    return __uint_as_float(u & 0xffff0000u);
}
// rounded hi + rounded residual lo: hi is BIT-IDENTICAL to f2bf(f) (the
// gather source), and hi+lo reconstructs f to ~2^-17 relative.
__device__ __forceinline__ void split_rbf(float f, unsigned short& ho,
                                          unsigned short& lo) {
    unsigned short hb = f2bf(f);
    ho = hb;
    lo = f2bf(f - bf2f(hb));
}

// ws layout (4B units) — AUDITED (u16 plane = N*64 u16 = 3,200,000 dwords):
//   counts : [0, 100352)
//   ovfc 100352 ; spillc 100353
//   gcur   : [100416, 100928)
//   ovf    : [100928, 109120)
//   spill  : [109120, 117312)
//   Bf1    : s16 [117312, 133696)
//   Bf2    : s16 [133696, 150080)
//   slots  : [150080, 6572608)        100352*64 dwords
//   rec    : u32 [6572608, 8178240)   392*4096
//   xh     : u16 [8178240,  11378240) 3.2M dwords = 6.4M u16
//   xl     : u16 [11378240, 14578240)
//   mh     : u16 [14578240, 17778240)
//   ml     : u16 [17778240, 20978240)
//   p_bf   : u16 [20978240, 24178240)
//   q      : f32 [24178240, 30578240)
// total 30,578,240 dwords = 122.3 MB

// Merged init + weight-split + x -> rounded-hi/residual-lo planes.
__global__ __launch_bounds__(256) void prep_kernel(
        const float4* __restrict__ x4,
        ushort4* __restrict__ xh4, ushort4* __restrict__ xl4,
        const float* __restrict__ W1l, const float* __restrict__ W1r,
        const float* __restrict__ W2l, const float* __restrict__ W2r,
        short* __restrict__ Bf1, short* __restrict__ Bf2,
        int4* __restrict__ gcur4, int* __restrict__ ovfc,
        int* __restrict__ spillc) {
    int i = blockIdx.x * blockDim.x + threadIdx.x;
    if (i < 128) gcur4[i] = make_int4(0, 0, 0, 0);
    if (i == 0) { *ovfc = 0; *spillc = 0; }
    if (i < 32768) {
        int g = i >> 14;
        int e = i & 16383;
        int k = e >> 7;
        int n = e & 127;
        float v;
        if (g == 0) v = (k < 64) ? W1l[k * 128 + n] : W1r[(k - 64) * 128 + n];
        else        v = (n < 64) ? W2l[k * 64 + n]  : W2r[k * 64 + (n - 64)];
        unsigned short hb, lb;
        split_rbf(v, hb, lb);
        int c = n >> 4, kc = k >> 5;
        int lane = (((k >> 3) & 3) << 4) | (n & 15);
        int j = k & 7;
        short* base = g ? Bf2 : Bf1;
        base[((c * 4 + kc) * 2 + 0) * 512 + lane * 8 + j] = (short)hb;
        base[((c * 4 + kc) * 2 + 1) * 512 + lane * 8 + j] = (short)lb;
    }
    if (i < N_NODES * 16) {
        float4 v = x4[i];
        ushort4 oh, ol;
        split_rbf(v.x, oh.x, ol.x);
        split_rbf(v.y, oh.y, ol.y);
        split_rbf(v.z, oh.z, ol.z);
        split_rbf(v.w, oh.w, ol.w);
        xh4[i] = oh;
        xl4[i] = ol;
    }
}

// Pass A: bin edges into 392 dst-range buckets via LDS FIFOs.
__global__ __launch_bounds__(256) void bin_kernel(
        const int* __restrict__ ei, unsigned* __restrict__ rec,
        int* __restrict__ gcur, int* __restrict__ spillc,
        int2* __restrict__ spill) {
    __shared__ int lcnt[NBKT];
    __shared__ unsigned fifo[NBKT * FIFO_CAP];   // 50KB
    for (int i = threadIdx.x; i < NBKT; i += 256) lcnt[i] = 0;
    __syncthreads();
    int base = blockIdx.x * BIN_CHUNK;
    int end = base + BIN_CHUNK;
    if (end > N_EDGES) end = N_EDGES;
    for (int e = base + threadIdx.x; e < end; e += 256) {
        int s = ei[e];
        int d = ei[N_EDGES + e];
        int b = d >> BKT_SH;
        unsigned r = ((unsigned)s << BKT_SH) | (unsigned)(d & (BKT_NODES - 1));
        int pos = atomicAdd(&lcnt[b], 1);
        if (pos < FIFO_CAP) {
            fifo[b * FIFO_CAP + pos] = r;
        } else {
            int o = atomicAdd(spillc, 1);
            if (o < SPILL_CAP) spill[o] = make_int2(s, d);
        }
    }
    __syncthreads();
    for (int b = threadIdx.x; b < NBKT; b += 256) {
        int cnt = lcnt[b];
        if (cnt > FIFO_CAP) cnt = FIFO_CAP;
        if (cnt == 0) continue;
        int gb = atomicAdd(&gcur[b], cnt);
        for (int k = 0; k < cnt; ++k) {
            int g = gb + k;
            unsigned r = fifo[b * FIFO_CAP + k];
            if (g < BKT_CAP) {
                rec[b * BKT_CAP + g] = r;
            } else {
                int o = atomicAdd(spillc, 1);
                if (o < SPILL_CAP)
                    spill[o] = make_int2((int)(r >> BKT_SH),
                                         (b << BKT_SH) | (int)(r & (BKT_NODES - 1)));
            }
        }
    }
}

// Pass B: one block per bucket; counts + slots tile built in LDS (65KB),
// written out fully coalesced. Spill entries handled inline.
__global__ __launch_bounds__(256) void build_kernel(
        const unsigned* __restrict__ rec, const int* __restrict__ gcur,
        const int2* __restrict__ spill, const int* __restrict__ spillc,
        int* __restrict__ counts, int* __restrict__ slots,
        int* __restrict__ ovfc, int* __restrict__ ovf) {
    __shared__ int lcnt[BKT_NODES];
    __shared__ int lslots[BKT_NODES * DEG_CAP];   // 64KB
    int b = blockIdx.x;
    for (int i = threadIdx.x; i < BKT_NODES; i += 256) lcnt[i] = 0;
    __syncthreads();
    int n = gcur[b];
    if (n > BKT_CAP) n = BKT_CAP;
    for (int i = threadIdx.x; i < n; i += 256) {
        unsigned r = rec[b * BKT_CAP + i];
        int dlo = (int)(r & (BKT_NODES - 1));
        int src = (int)(r >> BKT_SH);
        int pos = atomicAdd(&lcnt[dlo], 1);
        if (pos < DEG_CAP) {
            lslots[dlo * DEG_CAP + pos] = src;
        } else {
            int o = atomicAdd(ovfc, 1);
            if (o < OVF_CAP) {
                ovf[o * 2] = src;
                ovf[o * 2 + 1] = (b << BKT_SH) | dlo;
            }
        }
    }
    // inline spill handling (usually ns == 0)
    int ns = *spillc;
    if (ns > SPILL_CAP) ns = SPILL_CAP;
    for (int i = threadIdx.x; i < ns; i += 256) {
        int2 e = spill[i];
        if ((e.y >> BKT_SH) == b) {
            int dlo = e.y & (BKT_NODES - 1);
            int pos = atomicAdd(&lcnt[dlo], 1);
            if (pos < DEG_CAP) {
                lslots[dlo * DEG_CAP + pos] = e.x;
            } else {
                int o = atomicAdd(ovfc, 1);
                if (o < OVF_CAP) { ovf[o * 2] = e.x; ovf[o * 2 + 1] = e.y; }
            }
        }
    }
    __syncthreads();
    int nodeBase = b << BKT_SH;
    for (int i = threadIdx.x; i < BKT_NODES; i += 256)
        counts[nodeBase + i] = lcnt[i];
    const int4* ls4 = (const int4*)lslots;
    int4* gs4 = (int4*)(slots + nodeBase * DEG_CAP);
    for (int i = threadIdx.x; i < BKT_NODES * DEG_CAP / 4; i += 256)
        gs4[i] = ls4[i];
}

// Layer-1 gather, 16-lane-group-per-node (16 nodes/block). Lane t owns
// features 4t..4t+3; a group's 16 lanes load one full 128B neighbor row
// per instruction. Inner loop unrolled 4-wide with independent temps ->
// ~4x the outstanding loads of the old 1-wave-per-node form (which had
// only ~2 iterations at mean deg 10 and was latency-bound). No reduce
// tree, no divergent epilogue.
__global__ __launch_bounds__(256) void gather_bf_kernel(
        const unsigned short* __restrict__ feat, const int* __restrict__ counts,
        const int* __restrict__ slots,
        unsigned short* __restrict__ mh, unsigned short* __restrict__ ml) {
    int node = blockIdx.x * 16 + (threadIdx.x >> 4);
    int t = threadIdx.x & 15;
    if (node >= N_NODES) return;
    int deg = counts[node];
    int dcap = min(deg, DEG_CAP);
    const int gbase = threadIdx.x & 48;   // group's lane base within wave
    float a0 = 0.f, a1 = 0.f, a2 = 0.f, a3 = 0.f;
    for (int phase = 0; phase * 16 < dcap; ++phase) {
        int ids16 = slots[node * DEG_CAP + phase * 16 + t];
        int lim = min(dcap - phase * 16, 16);
        int j = 0;
        for (; j + 4 <= lim; j += 4) {
            int s0 = __shfl(ids16, gbase | (j + 0));
            int s1 = __shfl(ids16, gbase | (j + 1));
            int s2 = __shfl(ids16, gbase | (j + 2));
            int s3 = __shfl(ids16, gbase | (j + 3));
            uint2 u0 = *(const uint2*)(feat + s0 * 64 + t * 4);
            uint2 u1 = *(const uint2*)(feat + s1 * 64 + t * 4);
            uint2 u2 = *(const uint2*)(feat + s2 * 64 + t * 4);
            uint2 u3 = *(const uint2*)(feat + s3 * 64 + t * 4);
            a0 += bflo(u0.x) + bflo(u1.x) + bflo(u2.x) + bflo(u3.x);
            a1 += bfhi(u0.x) + bfhi(u1.x) + bfhi(u2.x) + bfhi(u3.x);
            a2 += bflo(u0.y) + bflo(u1.y) + bflo(u2.y) + bflo(u3.y);
            a3 += bfhi(u0.y) + bfhi(u1.y) + bfhi(u2.y) + bfhi(u3.y);
        }
        for (; j < lim; ++j) {
            int s = __shfl(ids16, gbase | j);
            uint2 u = *(const uint2*)(feat + s * 64 + t * 4);
            a0 += bflo(u.x);
            a1 += bfhi(u.x);
            a2 += bflo(u.y);
            a3 += bfhi(u.y);
        }
    }
    float inv = 1.0f / fmaxf((float)deg, 1.0f);
    ushort4 oh, ol;
    split_rbf(a0 * inv, oh.x, ol.x);
    split_rbf(a1 * inv, oh.y, ol.y);
    split_rbf(a2 * inv, oh.z, ol.z);
    split_rbf(a3 * inv, oh.w, ol.w);
    *(ushort4*)&mh[node * 64 + t * 4] = oh;
    *(ushort4*)&ml[node * 64 + t * 4] = ol;
}

// FUSED MLP, 128-row tiles, 4 waves × 2 col-tiles (measured optimum).
// Preamble: layer-1 overflow fix for rows in this block's range.
__global__ __launch_bounds__(256) void mlp_fused_kernel(
        const unsigned short* __restrict__ mh, const unsigned short* __restrict__ ml,
        const unsigned short* __restrict__ xh, const unsigned short* __restrict__ xl,
        const float* __restrict__ x,
        const short* __restrict__ Bf1, const float* __restrict__ b1,
        const short* __restrict__ Bf2, const float* __restrict__ b2,
        const int* __restrict__ ovf, const int* __restrict__ ovfc,
        const int* __restrict__ counts,
        unsigned short* __restrict__ p_bf_out, float* __restrict__ q) {
    __shared__ unsigned short h_lds[128][136];   // 34816 B
    const int w = threadIdx.x >> 6;
    const int l = threadIdx.x & 63;
    const int lane15 = l & 15;
    const int quad = l >> 4;
    const int rowBase = blockIdx.x * 128;

    // ---- preamble: layer-1 overflow fix for this block's rows ----
    {
        int n = *ovfc;
        if (n > OVF_CAP) n = OVF_CAP;
        if (n > 0) {
            for (int idx = 0; idx < n; ++idx) {
                int d = ovf[idx * 2 + 1];
                if (d >= rowBase && d < rowBase + 128) {
                    if (threadIdx.x < 64) {
                        int s = ovf[idx * 2];
                        int t = threadIdx.x;
                        float inv = 1.0f / fmaxf((float)counts[d], 1.0f);
                        float m = bf2f(mh[d * 64 + t]) + bf2f(ml[d * 64 + t])
                                + x[s * 64 + t] * inv;
                        unsigned short hb, lb;
                        split_rbf(m, hb, lb);
                        ((unsigned short*)mh)[d * 64 + t] = hb;
                        ((unsigned short*)ml)[d * 64 + t] = lb;
                    }
                    __syncthreads();
                }
            }
            __syncthreads();
        }
    }

    // ---- phase 1: layer 1, B-stationary, 3-MFMA hi/lo split ----
    {
        bf16x8 bh[2][4], bl[2][4];
#pragma unroll
        for (int ci = 0; ci < 2; ++ci) {
            const int c = 2 * w + ci;
#pragma unroll
            for (int kc = 0; kc < 4; ++kc) {
                const short* bp = Bf1 + ((c * 4 + kc) * 2) * 512 + l * 8;
                bh[ci][kc] = *(const bf16x8*)bp;
                bl[ci][kc] = *(const bf16x8*)(bp + 512);
            }
        }
        float bias[2];
#pragma unroll
        for (int ci = 0; ci < 2; ++ci) bias[ci] = b1[(2 * w + ci) * 16 + lane15];

#pragma unroll
        for (int rt = 0; rt < 8; ++rt) {
            const int row = rowBase + rt * 16 + lane15;
            const bool rv = row < N_NODES;
            const bf16x8 zz = {0, 0, 0, 0, 0, 0, 0, 0};

            bf16x8 ah[4], al[4];
#pragma unroll
            for (int kc = 0; kc < 4; ++kc) {
                if (rv) {
                    const int off = (kc < 2)
                        ? row * 64 + kc * 32 + quad * 8
                        : row * 64 + (kc - 2) * 32 + quad * 8;
                    const unsigned short* ph = (kc < 2) ? (mh + off) : (xh + off);
                    const unsigned short* pl = (kc < 2) ? (ml + off) : (xl + off);
                    ah[kc] = *(const bf16x8*)ph;
                    al[kc] = *(const bf16x8*)pl;
                } else {
                    ah[kc] = zz;
                    al[kc] = zz;
                }
            }

            f32x4 acc[2] = {(f32x4){0.f, 0.f, 0.f, 0.f}, (f32x4){0.f, 0.f, 0.f, 0.f}};
#pragma unroll
            for (int kc = 0; kc < 4; ++kc) {
#pragma unroll
                for (int ci = 0; ci < 2; ++ci) {
                    acc[ci] = __builtin_amdgcn_mfma_f32_16x16x32_bf16(ah[kc], bh[ci][kc], acc[ci], 0, 0, 0);
                    acc[ci] = __builtin_amdgcn_mfma_f32_16x16x32_bf16(al[kc], bh[ci][kc], acc[ci], 0, 0, 0);
                    acc[ci] = __builtin_amdgcn_mfma_f32_16x16x32_bf16(ah[kc], bl[ci][kc], acc[ci], 0, 0, 0);
                }
            }

            const int rloc = rt * 16 + quad * 4;
#pragma unroll
            for (int ci = 0; ci < 2; ++ci) {
                const int col = (2 * w + ci) * 16 + lane15;
#pragma unroll
                for (int i = 0; i < 4; ++i)
                    h_lds[rloc + i][col] =
                        f2bf(fmaxf(acc[ci][i] + bias[ci], 0.f));
            }
        }
    }
    __syncthreads();

    // ---- phase 2: layer 2 from LDS (A = bf16, W2 keeps hi/lo split) ----
    {
        bf16x8 bh[2][4], bl[2][4];
#pragma unroll
        for (int ci = 0; ci < 2; ++ci) {
            const int c = 2 * w + ci;
#pragma unroll
            for (int kc = 0; kc < 4; ++kc) {
                const short* bp = Bf2 + ((c * 4 + kc) * 2) * 512 + l * 8;
                bh[ci][kc] = *(const bf16x8*)bp;
                bl[ci][kc] = *(const bf16x8*)(bp + 512);
            }
        }
        float bias[2];
#pragma unroll
        for (int ci = 0; ci < 2; ++ci) {
            const int c = 2 * w + ci;
            bias[ci] = (c >= 4) ? b2[(c - 4) * 16 + lane15] : 0.f;
        }

#pragma unroll
        for (int rt = 0; rt < 8; ++rt) {
            bf16x8 ah[4];
#pragma unroll
            for (int kc = 0; kc < 4; ++kc)
                ah[kc] = *(const bf16x8*)&h_lds[rt * 16 + lane15][kc * 32 + quad * 8];

            f32x4 acc[2] = {(f32x4){0.f, 0.f, 0.f, 0.f}, (f32x4){0.f, 0.f, 0.f, 0.f}};
#pragma unroll
            for (int kc = 0; kc < 4; ++kc) {
#pragma unroll
                for (int ci = 0; ci < 2; ++ci) {
                    acc[ci] = __builtin_amdgcn_mfma_f32_16x16x32_bf16(ah[kc], bh[ci][kc], acc[ci], 0, 0, 0);
                    acc[ci] = __builtin_amdgcn_mfma_f32_16x16x32_bf16(ah[kc], bl[ci][kc], acc[ci], 0, 0, 0);
                }
            }

            const int rb = rowBase + rt * 16 + quad * 4;
#pragma unroll
            for (int ci = 0; ci < 2; ++ci) {
                const int c = 2 * w + ci;
                if (c < 4) {
#pragma unroll
                    for (int i = 0; i < 4; ++i) {
                        int r = rb + i;
                        if (r < N_NODES)
                            p_bf_out[r * 64 + c * 16 + lane15] = f2bf(acc[ci][i]);
                    }
                } else {
#pragma unroll
                    for (int i = 0; i < 4; ++i) {
                        int r = rb + i;
                        if (r < N_NODES)
                            q[r * 64 + (c - 4) * 16 + lane15] = acc[ci][i] + bias[ci];
                    }
                }
            }
        }
    }
}

// Layer-2 gather + epilogue, 16-lane-group-per-node (same MLP-boosting
// structure as gather_bf). out = mean(p_bf[nbrs]) + q, ovf added inline.
__global__ __launch_bounds__(256) void gather_final_kernel(
        const unsigned short* __restrict__ p, const int* __restrict__ counts,
        const int* __restrict__ slots, const float* __restrict__ q,
        const int* __restrict__ ovf, const int* __restrict__ ovfc,
        float* __restrict__ out) {
    int node = blockIdx.x * 16 + (threadIdx.x >> 4);
    int t = threadIdx.x & 15;
    if (node >= N_NODES) return;
    int deg = counts[node];
    int dcap = min(deg, DEG_CAP);
    const int gbase = threadIdx.x & 48;
    float a0 = 0.f, a1 = 0.f, a2 = 0.f, a3 = 0.f;
    for (int phase = 0; phase * 16 < dcap; ++phase) {
        int ids16 = slots[node * DEG_CAP + phase * 16 + t];
        int lim = min(dcap - phase * 16, 16);
        int j = 0;
        for (; j + 4 <= lim; j += 4) {
            int s0 = __shfl(ids16, gbase | (j + 0));
            int s1 = __shfl(ids16, gbase | (j + 1));
            int s2 = __shfl(ids16, gbase | (j + 2));
            int s3 = __shfl(ids16, gbase | (j + 3));
            uint2 u0 = *(const uint2*)(p + s0 * 64 + t * 4);
            uint2 u1 = *(const uint2*)(p + s1 * 64 + t * 4);
            uint2 u2 = *(const uint2*)(p + s2 * 64 + t * 4);
            uint2 u3 = *(const uint2*)(p + s3 * 64 + t * 4);
            a0 += bflo(u0.x) + bflo(u1.x) + bflo(u2.x) + bflo(u3.x);
            a1 += bfhi(u0.x) + bfhi(u1.x) + bfhi(u2.x) + bfhi(u3.x);
            a2 += bflo(u0.y) + bflo(u1.y) + bflo(u2.y) + bflo(u3.y);
            a3 += bfhi(u0.y) + bfhi(u1.y) + bfhi(u2.y) + bfhi(u3.y);
        }
        for (; j < lim; ++j) {
            int s = __shfl(ids16, gbase | j);
            uint2 u = *(const uint2*)(p + s * 64 + t * 4);
            a0 += bflo(u.x);
            a1 += bfhi(u.x);
            a2 += bflo(u.y);
            a3 += bfhi(u.y);
        }
    }
    // inline layer-2 overflow additions (n is ~always 0)
    int n = *ovfc;
    if (n > OVF_CAP) n = OVF_CAP;
    for (int idx = 0; idx < n; ++idx) {
        if (ovf[idx * 2 + 1] == node) {
            int s = ovf[idx * 2];
            uint2 u = *(const uint2*)(p + s * 64 + t * 4);
            a0 += bflo(u.x);
            a1 += bfhi(u.x);
            a2 += bflo(u.y);
            a3 += bfhi(u.y);
        }
    }
    float inv = 1.0f / fmaxf((float)deg, 1.0f);
    float4 qv = *(const float4*)&q[node * 64 + t * 4];
    *(float4*)&out[node * 64 + t * 4] =
        make_float4(a0 * inv + qv.x, a1 * inv + qv.y,
                    a2 * inv + qv.z, a3 * inv + qv.w);
}

extern "C" void kernel_launch(void* const* d_in, const int* in_sizes, int n_in,
                              void* d_out, int out_size, void* d_ws, size_t ws_size,
                              hipStream_t stream) {
    const float* x   = (const float*)d_in[0];
    const float* W1l = (const float*)d_in[1];
    const float* W1r = (const float*)d_in[2];
    const float* b1  = (const float*)d_in[3];
    const float* W2l = (const float*)d_in[4];
    const float* W2r = (const float*)d_in[5];
    const float* b2  = (const float*)d_in[6];
    const int*   ei  = (const int*)d_in[7];

    int*   wsi      = (int*)d_ws;
    float* wsf      = (float*)d_ws;
    int*   counts   = wsi;
    int*   ovfc     = wsi + 100352;
    int*   spillc   = wsi + 100353;
    int*   gcur     = wsi + 100416;
    int*   ovf      = wsi + 100928;
    int2*  spill    = (int2*)(wsi + 109120);
    short* Bf1      = (short*)(wsi + 117312);
    short* Bf2      = (short*)(wsi + 133696);
    int*   slots    = wsi + 150080;
    unsigned* rec   = (unsigned*)(wsi + 6572608);
    unsigned short* xh = (unsigned short*)(wsi + 8178240);
    unsigned short* xl = (unsigned short*)(wsi + 11378240);
    unsigned short* mh = (unsigned short*)(wsi + 14578240);
    unsigned short* ml = (unsigned short*)(wsi + 17778240);
    unsigned short* p_bf = (unsigned short*)(wsi + 20978240);
    float* q        = wsf + 24178240;
    float* out      = (float*)d_out;

    prep_kernel<<<(N_NODES * 16 + 255) / 256, 256, 0, stream>>>(
        (const float4*)x, (ushort4*)xh, (ushort4*)xl, W1l, W1r, W2l, W2r,
        Bf1, Bf2, (int4*)gcur, ovfc, spillc);

    // indexing: LDS-binned two-pass (spill handled inside build)
    bin_kernel<<<(N_EDGES + BIN_CHUNK - 1) / BIN_CHUNK, 256, 0, stream>>>(
        ei, rec, gcur, spillc, spill);
    build_kernel<<<NBKT, 256, 0, stream>>>(
        rec, gcur, spill, spillc, counts, slots, ovfc, ovf);

    // layer-1 aggregation -> mean hi/lo planes (16 nodes/block)
    gather_bf_kernel<<<(N_NODES + 15) / 16, 256, 0, stream>>>(
        xh, counts, slots, mh, ml);

    // fused MLP (ovf preamble inside): h (LDS) -> p_bf, q
    mlp_fused_kernel<<<(N_NODES + 127) / 128, 256, 0, stream>>>(
        mh, ml, xh, xl, x, Bf1, b1, Bf2, b2, ovf, ovfc, counts, p_bf, q);

    // fused layer-2 aggregation + epilogue (ovf additions inside)
    gather_final_kernel<<<(N_NODES + 15) / 16, 256, 0, stream>>>(
        p_bf, counts, slots, q, ovf, ovfc, out);
}